// Round 11
// baseline (150.145 us; speedup 1.0000x reference)
//
#include <hip/hip_runtime.h>

#define NB 2
#define LX 2048
#define LZ 2048
#define HH 16
#define DA 64
#define DM 64
#define HD 1024
#define MINF  -1000000.0f
#define QSC   0.1803368801f   // 0.125 * log2(e): softmax done in base-2 domain
#define DTHR  8.0f            // defer-max threshold (base-2): P <= 2^8

typedef __attribute__((ext_vector_type(8))) short short8;
typedef __attribute__((ext_vector_type(4))) float f32x4;

static __device__ __forceinline__ ushort f2bf(float f) {
    union { float f; uint32_t u; } c; c.f = f;
    return (ushort)((c.u + 0x7FFFu + ((c.u >> 16) & 1u)) >> 16);
}

static __device__ __forceinline__ float bf2f(ushort u) {
    union { uint32_t u; float f; } c; c.u = (uint32_t)u << 16;
    return c.f;
}

static __device__ __forceinline__ uint32_t cvtpk(float lo, float hi) {
    uint32_t r;
    asm("v_cvt_pk_bf16_f32 %0, %1, %2" : "=v"(r) : "v"(lo), "v"(hi));
    return r;
}

#define GL16(g, l) __builtin_amdgcn_global_load_lds( \
    (const __attribute__((address_space(1))) void*)(g), \
    (__attribute__((address_space(3))) void*)(l), 16, 0, 0)

// ---------------------------------------------------------------------------
// fp32 -> bf16 for both activations in one launch. 8192 blocks.
// ---------------------------------------------------------------------------
__global__ __launch_bounds__(256) void cvt_both(
    const float* __restrict__ pA, const float* __restrict__ pB,
    ushort* __restrict__ oA, ushort* __restrict__ oB)
{
    const int i = blockIdx.x * 256 + threadIdx.x;      // 0..2097151
    const float* in = (i < 1048576) ? pA : pB;
    ushort* out = (i < 1048576) ? oA : oB;
    const int j = i & 1048575;
    float4 v = ((const float4*)in)[j];
    ushort4 o;
    o.x = f2bf(v.x); o.y = f2bf(v.y); o.z = f2bf(v.z); o.w = f2bf(v.w);
    ((ushort4*)out)[j] = o;
}

// ---------------------------------------------------------------------------
// 4 weights W[1024][1024] f32 -> Wt[1024][1024] bf16 transposed, one launch.
// ---------------------------------------------------------------------------
__global__ __launch_bounds__(256) void wtrans4(
    const float* __restrict__ W0, const float* __restrict__ W1,
    const float* __restrict__ W2, const float* __restrict__ W3,
    ushort* __restrict__ T0, ushort* __restrict__ T1,
    ushort* __restrict__ T2, ushort* __restrict__ T3)
{
    const int zz = blockIdx.z;
    const float* W = (zz == 0) ? W0 : (zz == 1) ? W1 : (zz == 2) ? W2 : W3;
    ushort* Wt = (zz == 0) ? T0 : (zz == 1) ? T1 : (zz == 2) ? T2 : T3;

    __shared__ ushort Ls[64][72];
    const int n0 = blockIdx.x * 64, k0 = blockIdx.y * 64;
    const int t = threadIdx.x;
    const int rr = t >> 4, c4 = (t & 15) * 4;
    #pragma unroll
    for (int i = 0; i < 4; ++i) {
        const int r = rr + i * 16;
        float4 v = *(const float4*)&W[(size_t)(k0 + r) * 1024 + n0 + c4];
        Ls[c4 + 0][r] = f2bf(v.x);
        Ls[c4 + 1][r] = f2bf(v.y);
        Ls[c4 + 2][r] = f2bf(v.z);
        Ls[c4 + 3][r] = f2bf(v.w);
    }
    __syncthreads();
    const int n = t >> 2, kc = (t & 3) * 16;
    *(short8*)&Wt[(size_t)(n0 + n) * 1024 + k0 + kc]     = *(const short8*)&Ls[n][kc];
    *(short8*)&Wt[(size_t)(n0 + n) * 1024 + k0 + kc + 8] = *(const short8*)&Ls[n][kc + 8];
}

// ---------------------------------------------------------------------------
// bf16 MFMA GEMM (m97 structure): C = A[M][1024] @ Bt[1024][1024]^T, bf16 out.
// 128x128 tile, BK=32, 4 waves, global_load_lds(16B). Used for Q/K/V.
// ---------------------------------------------------------------------------
__global__ __launch_bounds__(256) void gemm_qkv(
    const ushort* __restrict__ Pb, const ushort* __restrict__ Cb,
    const ushort* __restrict__ Wqt, const ushort* __restrict__ Wkt,
    const ushort* __restrict__ Wvt,
    ushort* __restrict__ Qb, ushort* __restrict__ Kb, ushort* __restrict__ Vb)
{
    const int z = blockIdx.z;
    const ushort* A  = (z == 0) ? Pb : Cb;
    const ushort* Bt = (z == 0) ? Wqt : (z == 1) ? Wkt : Wvt;
    ushort* Cout = (z == 0) ? Qb : (z == 1) ? Kb : Vb;
    const float osc = (z == 0) ? QSC : 1.0f;   // fold softmax scale*log2e into Q

    __shared__ ushort As[128 * 32];
    __shared__ ushort Bs[128 * 32];
    const int t = threadIdx.x;
    const int w = t >> 6, l = t & 63, lr = l & 15, lg = l >> 4;
    const int wr = w >> 1, wc = w & 1;
    const int n0 = blockIdx.x * 128, m0 = blockIdx.y * 128;

    const int c0 = t, c1 = t + 256;
    const ushort* a0 = &A[(size_t)(m0 + (c0 >> 2)) * 1024 + (c0 & 3) * 8];
    const ushort* a1 = &A[(size_t)(m0 + (c1 >> 2)) * 1024 + (c1 & 3) * 8];
    const ushort* b0 = &Bt[(size_t)(n0 + (c0 >> 2)) * 1024 + (c0 & 3) * 8];
    const ushort* b1 = &Bt[(size_t)(n0 + (c1 >> 2)) * 1024 + (c1 & 3) * 8];
    ushort* lA0 = &As[w * 512];
    ushort* lA1 = &As[(4 + w) * 512];
    ushort* lB0 = &Bs[w * 512];
    ushort* lB1 = &Bs[(4 + w) * 512];

    f32x4 acc[4][4];
    #pragma unroll
    for (int i = 0; i < 4; ++i)
        #pragma unroll
        for (int j = 0; j < 4; ++j) acc[i][j] = 0.f;

    for (int k0 = 0; k0 < 1024; k0 += 32) {
        __syncthreads();
        GL16(a0 + k0, lA0);
        GL16(a1 + k0, lA1);
        GL16(b0 + k0, lB0);
        GL16(b1 + k0, lB1);
        __syncthreads();
        short8 af[4], bf[4];
        #pragma unroll
        for (int mi = 0; mi < 4; ++mi)
            af[mi] = *(const short8*)&As[(wr * 64 + mi * 16 + lr) * 32 + lg * 8];
        #pragma unroll
        for (int nj = 0; nj < 4; ++nj)
            bf[nj] = *(const short8*)&Bs[(wc * 64 + nj * 16 + lr) * 32 + lg * 8];
        #pragma unroll
        for (int mi = 0; mi < 4; ++mi)
            #pragma unroll
            for (int nj = 0; nj < 4; ++nj)
                acc[mi][nj] = __builtin_amdgcn_mfma_f32_16x16x32_bf16(
                    af[mi], bf[nj], acc[mi][nj], 0, 0, 0);
    }

    const int row0 = m0 + wr * 64, col0 = n0 + wc * 64;
    #pragma unroll
    for (int mi = 0; mi < 4; ++mi)
        #pragma unroll
        for (int nj = 0; nj < 4; ++nj) {
            const int col = col0 + nj * 16 + lr;
            #pragma unroll
            for (int r = 0; r < 4; ++r) {
                const int row = row0 + mi * 16 + lg * 4 + r;
                Cout[(size_t)row * 1024 + col] = f2bf(acc[mi][nj][r] * osc);
            }
        }
}

// ---------------------------------------------------------------------------
// Classify each 64x64 mask tile: 0 = all masked, 1 = all pass, 2 = mixed.
// ---------------------------------------------------------------------------
__global__ __launch_bounds__(256) void mask_classify(
    const int* __restrict__ amask, const int* __restrict__ pmask,
    int* __restrict__ cls)
{
    const int bid = blockIdx.x;
    const int b = bid >> 10, xb = (bid >> 5) & 31, zb = bid & 31;
    const int t = threadIdx.x;
    int andv = 1, orv = 0;
    #pragma unroll
    for (int i = 0; i < 16; ++i) {
        const int e = t + i * 256;
        const int r = e >> 6, z = e & 63;
        const int m = amask[((size_t)b * LX + xb * 64 + r) * LZ + zb * 64 + z];
        const int p = pmask[(size_t)b * LZ + zb * 64 + z];
        const int v = (m != 0) & (p != 0);
        andv &= v; orv |= v;
    }
    __shared__ int sa[256];
    __shared__ int so[256];
    sa[t] = andv; so[t] = orv;
    __syncthreads();
    for (int s = 128; s > 0; s >>= 1) {
        if (t < s) { sa[t] &= sa[t + s]; so[t] |= so[t + s]; }
        __syncthreads();
    }
    if (t == 0) cls[bid] = so[0] ? (sa[0] ? 1 : 2) : 0;
}

// ---------------------------------------------------------------------------
// MFMA flash attention: split-KV x2, mi=2 (128 q-rows/block, wave owns 32),
// single K/V LDS buffer, balanced XCD clustering (round-9 mapping). Barriers,
// staging, and LDS traffic per unit work are HALF of the 64-row version; each
// wave carries 2 independent softmax/MFMA chains (ILP). Ballot walk over the
// union of both 64-row strips' active tiles; per-wave strip masks gate
// compute. Writes PARTIAL O (bf16) + (m,l) f32. Grid 1024 blocks.
// ---------------------------------------------------------------------------
__global__ __launch_bounds__(256, 4) void attn_mfma(
    const ushort* __restrict__ Qg, const ushort* __restrict__ Kg,
    const ushort* __restrict__ Vg, const int* __restrict__ amask,
    const int* __restrict__ pmask, const int* __restrict__ cls,
    ushort* __restrict__ Op, float2* __restrict__ ml)
{
    __shared__ ushort Ks[64 * 72];   // [z][d], pad 72
    __shared__ ushort Vt[64 * 64];   // [m][z], chunk-XOR swizzled

    const int t = threadIdx.x, w = t >> 6, l = t & 63, lr = l & 15, lg = l >> 4;
    // balanced XCD clustering: XCD x gets groups {x, x+8, ..., x+56}
    // -> every XCD sees all 4 (b,sKV) splits (round-10's g=xcd*8+.. was skewed)
    const int flat = blockIdx.x + 16 * (blockIdx.y + 16 * blockIdx.z); // 0..1023
    const int xcd = flat & 7, ii = flat >> 3;       // ii 0..127
    const int g = xcd + 8 * (ii >> 4);              // 0..63 (h,bs) group
    const int slot = ii & 15;
    const int h = g & 15, bs = g >> 4;              // bs 0..3
    const int b = bs & 1, sKV = bs >> 1;
    // load-balance remap within group (qb 0..15, 128 rows each)
    const int fx = (slot & 1) ? 15 - (slot >> 1) : (slot >> 1);
    const int qb = b ? 15 - fx : fx;
    const int qw = qb * 128 + w * 32;

    // masks: lane l reads cls strip (l>>5) of this q-block, col l&31
    const uint32_t halfm = sKV ? 0xAAAAAAAAu : 0x55555555u;
    const int cv = cls[b * 1024 + (qb * 2 + (l >> 5)) * 32 + (l & 31)];
    const unsigned long long balA = __ballot(cv != 0);
    const unsigned long long balM = __ballot(cv == 2);
    const uint32_t uA = ((uint32_t)balA | (uint32_t)(balA >> 32)) & halfm;
    const uint32_t aW = (uint32_t)((w < 2) ? balA : (balA >> 32)) & halfm;
    const uint32_t mW = (uint32_t)((w < 2) ? balM : (balM >> 32)) & halfm;

    const size_t obase = (size_t)((sKV * NB + b) * LX + qw) * HD + h * DM;
    const size_t mlbase = (size_t)((sKV * NB + b) * HH + h) * LX + qw;
    if (uA == 0) {                    // nothing in this half: zero partial
        if (l < 16) {
            ml[mlbase + l]      = make_float2(-1e30f, 0.f);
            ml[mlbase + 16 + l] = make_float2(-1e30f, 0.f);
        }
        #pragma unroll
        for (int mi = 0; mi < 2; ++mi)
            #pragma unroll
            for (int r = 0; r < 4; ++r)
                #pragma unroll
                for (int mj = 0; mj < 4; ++mj)
                    Op[obase + (size_t)(mi * 16 + (lg << 2) + r) * HD + mj * 16 + lr] = 0;
        return;
    }

    // Q B-frags: lane holds Q[q = mi*16+lr][d = ks*32 + lg*8 .. +8]
    short8 qf[2][2];
    #pragma unroll
    for (int mi = 0; mi < 2; ++mi)
        #pragma unroll
        for (int ks = 0; ks < 2; ++ks)
            qf[mi][ks] = *(const short8*)&Qg[(size_t)(b * LX + qw + mi * 16 + lr) * HD
                                             + h * DA + ks * 32 + lg * 8];

    float mrun[2] = {-1e30f, -1e30f}, lrun[2] = {0.f, 0.f};
    f32x4 o[2][4];
    #pragma unroll
    for (int mi = 0; mi < 2; ++mi)
        #pragma unroll
        for (int mj = 0; mj < 4; ++mj) o[mi][mj] = 0.f;

    const int kz = t >> 2, kc = (t & 3) * 16;      // K staging
    const int vz = (t >> 3) * 2, vc = (t & 7) * 8; // V staging (2 rows x 8 cols)

    uint32_t remw = uA;
    while (remw) {
        const int zb = __builtin_ctz(remw);
        remw &= remw - 1;
        const int z0 = zb * 64;

        __syncthreads();                // prior tile's LDS reads complete
        {
            const ushort* kp = &Kg[(size_t)(b * LZ + z0 + kz) * HD + h * DA + kc];
            *(short8*)&Ks[kz * 72 + kc]     = *(const short8*)kp;
            *(short8*)&Ks[kz * 72 + kc + 8] = *(const short8*)(kp + 8);
            const ushort* vp = &Vg[(size_t)(b * LZ + z0 + vz) * HD + h * DM + vc];
            short8 v0 = *(const short8*)vp;
            short8 v1 = *(const short8*)(vp + HD);
            const int zc = vz >> 3, zo = vz & 7;
            #pragma unroll
            for (int j = 0; j < 8; ++j) {
                const int m = vc + j;
                const int idx = m * 64 + (((zc ^ m ^ (m >> 3)) & 7) << 3) + zo;
                *(uint32_t*)&Vt[idx] =
                    (uint32_t)(ushort)v0[j] | ((uint32_t)(ushort)v1[j] << 16);
            }
        }
        __syncthreads();

        if (!((aW >> zb) & 1)) continue;       // wave's strip inactive here
        const bool mixed = (mW >> zb) & 1;

        // ---- S^T = K @ Q : lane holds S[q=mi*16+lr][z = nj*16 + lg*4 + r] ----
        f32x4 s[2][4];
        __builtin_amdgcn_s_setprio(1);
        #pragma unroll
        for (int nj = 0; nj < 4; ++nj) {
            const short8 kf0 = *(const short8*)&Ks[(nj * 16 + lr) * 72 + lg * 8];
            const short8 kf1 = *(const short8*)&Ks[(nj * 16 + lr) * 72 + 32 + lg * 8];
            #pragma unroll
            for (int mi = 0; mi < 2; ++mi) {
                f32x4 z4 = 0.f;
                z4 = __builtin_amdgcn_mfma_f32_16x16x32_bf16(kf0, qf[mi][0], z4, 0, 0, 0);
                z4 = __builtin_amdgcn_mfma_f32_16x16x32_bf16(kf1, qf[mi][1], z4, 0, 0, 0);
                s[mi][nj] = z4;
            }
        }
        __builtin_amdgcn_s_setprio(0);
        // ---- mask (mixed tiles only) ----
        if (mixed) {
            #pragma unroll
            for (int mi = 0; mi < 2; ++mi) {
                const size_t arow = (size_t)(b * LX + qw + mi * 16 + lr) * LZ + z0;
                #pragma unroll
                for (int nj = 0; nj < 4; ++nj)
                    #pragma unroll
                    for (int r = 0; r < 4; ++r) {
                        const int z = nj * 16 + lg * 4 + r;
                        const int ok = (amask[arow + z] != 0) & (pmask[b * LZ + z0 + z] != 0);
                        if (!ok) s[mi][nj][r] = MINF;
                    }
            }
        }
        // ---- online softmax, base-2, defer-max (row stats live at q=lr) ----
        #pragma unroll
        for (int mi = 0; mi < 2; ++mi) {
            float pm = s[mi][0][0];
            #pragma unroll
            for (int nj = 0; nj < 4; ++nj)
                #pragma unroll
                for (int r = 0; r < 4; ++r) pm = fmaxf(pm, s[mi][nj][r]);
            pm = fmaxf(pm, __shfl_xor(pm, 16));
            pm = fmaxf(pm, __shfl_xor(pm, 32));
            if (__any(pm > mrun[mi] + DTHR)) {
                const float mn = fmaxf(mrun[mi], pm);
                const float al = exp2f(mrun[mi] - mn);
                mrun[mi] = mn;
                lrun[mi] *= al;
                #pragma unroll
                for (int r = 0; r < 4; ++r) {
                    const float alq = __shfl(al, (lg << 2) + r);
                    #pragma unroll
                    for (int mj = 0; mj < 4; ++mj) o[mi][mj][r] *= alq;
                }
            }
            #pragma unroll
            for (int nj = 0; nj < 4; ++nj)
                #pragma unroll
                for (int r = 0; r < 4; ++r) {
                    const float p = exp2f(s[mi][nj][r] - mrun[mi]);
                    s[mi][nj][r] = p;
                    lrun[mi] += p;   // per-lane partial; reduce at end
                }
        }
        // ---- P -> PV A-frags: pack own registers (sigma z-order) ----
        short8 pa[2][2];
        #pragma unroll
        for (int mi = 0; mi < 2; ++mi) {
            uint32_t pk01[4], pk23[4];
            #pragma unroll
            for (int nj = 0; nj < 4; ++nj) {
                pk01[nj] = cvtpk(s[mi][nj][0], s[mi][nj][1]);
                pk23[nj] = cvtpk(s[mi][nj][2], s[mi][nj][3]);
            }
            #pragma unroll
            for (int ks = 0; ks < 2; ++ks) {
                union { uint32_t d[4]; short8 v; } u;
                u.d[0] = pk01[2 * ks];
                u.d[1] = pk23[2 * ks];
                u.d[2] = pk01[2 * ks + 1];
                u.d[3] = pk23[2 * ks + 1];
                pa[mi][ks] = u.v;
            }
        }
        // ---- O += P @ V (V-frags shared across mi; sigma z-order b64s) ----
        __builtin_amdgcn_s_setprio(1);
        #pragma unroll
        for (int mj = 0; mj < 4; ++mj) {
            const int m_ = mj * 16 + lr;
            const int xr = (m_ ^ (m_ >> 3)) & 7;
            const int czb = lg >> 1;
            const int zo = (lg & 1) * 4;
            #pragma unroll
            for (int ks = 0; ks < 2; ++ks) {
                const int clo = (ks * 4 + czb) ^ xr;
                const int chi = (ks * 4 + 2 + czb) ^ xr;
                const uint2 lo = *(const uint2*)&Vt[m_ * 64 + ((clo & 7) << 3) + zo];
                const uint2 hi = *(const uint2*)&Vt[m_ * 64 + ((chi & 7) << 3) + zo];
                union { uint32_t d[4]; short8 v; } u;
                u.d[0] = lo.x; u.d[1] = lo.y; u.d[2] = hi.x; u.d[3] = hi.y;
                #pragma unroll
                for (int mi = 0; mi < 2; ++mi)
                    o[mi][mj] = __builtin_amdgcn_mfma_f32_16x16x32_bf16(
                        pa[mi][ks], u.v, o[mi][mj], 0, 0, 0);
            }
        }
        __builtin_amdgcn_s_setprio(0);
    }

    // ---- epilogue: finish l reduction, store partials (no normalize) ----
    #pragma unroll
    for (int mi = 0; mi < 2; ++mi) {
        lrun[mi] += __shfl_xor(lrun[mi], 16);
        lrun[mi] += __shfl_xor(lrun[mi], 32);
    }
    if (l < 16) {
        ml[mlbase + l]      = make_float2(mrun[0], lrun[0]);
        ml[mlbase + 16 + l] = make_float2(mrun[1], lrun[1]);
    }
    #pragma unroll
    for (int mi = 0; mi < 2; ++mi)
        #pragma unroll
        for (int r = 0; r < 4; ++r)
            #pragma unroll
            for (int mj = 0; mj < 4; ++mj)
                Op[obase + (size_t)(mi * 16 + (lg << 2) + r) * HD + mj * 16 + lr]
                    = f2bf(o[mi][mj][r]);
}

// ---------------------------------------------------------------------------
// Per-(row, head) combine weights: w_i = exp2(m_i - M) / L. 65536 threads.
// ---------------------------------------------------------------------------
__global__ __launch_bounds__(256) void mkw(
    const float2* __restrict__ ml, float2* __restrict__ wbuf)
{
    const int i = blockIdx.x * 256 + threadIdx.x;      // 0..65535
    const int row = i >> 4, h = i & 15;                // row = b*LX + x
    const int b = row >> 11, x = row & 2047;
    const float2 a0 = ml[(b * HH + h) * LX + x];
    const float2 a1 = ml[NB * HH * LX + (b * HH + h) * LX + x];
    const float M = fmaxf(a0.x, a1.x);
    const float w0 = exp2f(a0.x - M), w1 = exp2f(a1.x - M);
    const float inv = 1.f / fmaxf(a0.y * w0 + a1.y * w1, 1e-37f);
    wbuf[i] = make_float2(w0 * inv, w1 * inv);
}

// ---------------------------------------------------------------------------
// Output GEMM with FUSED split-KV combine: A[row][k] is built on the fly from
// the two attention partials (Op0/Op1) and wbuf weights during LDS staging.
// Tile 64x128 (grid 512 = 2 blocks/CU), BK=32, 4 waves (wave = 32x64).
// fp32 out + bias.
// ---------------------------------------------------------------------------
__global__ __launch_bounds__(256) void gemm_out_fused(
    const ushort* __restrict__ Op, const float2* __restrict__ wbuf,
    const ushort* __restrict__ Bt, const float* __restrict__ bias,
    float* __restrict__ Cout)
{
    __shared__ ushort As[64 * 32];
    __shared__ ushort Bs[128 * 32];
    const int t = threadIdx.x;
    const int w = t >> 6, l = t & 63, lr = l & 15, lg = l >> 4;
    const int wr = w >> 1, wc = w & 1;
    const int n0 = blockIdx.x * 128, m0 = blockIdx.y * 64;

    // A: 256 chunks (64 rows x 4 k-chunks), one per thread
    const int ra = m0 + (t >> 2), ka = (t & 3) * 8;
    const ushort* p0 = &Op[(size_t)ra * HD + ka];
    const ushort* p1 = p0 + (size_t)NB * LX * HD;
    const float2* wrow = &wbuf[ra * 16];
    // B: 512 chunks, two per thread
    const ushort* b0 = &Bt[(size_t)(n0 + (t >> 2)) * 1024 + ka];
    const ushort* b1 = &Bt[(size_t)(n0 + 64 + (t >> 2)) * 1024 + ka];
    ushort* lB0 = &Bs[w * 512];
    ushort* lB1 = &Bs[(4 + w) * 512];

    f32x4 acc[2][4];
    #pragma unroll
    for (int i = 0; i < 2; ++i)
        #pragma unroll
        for (int j = 0; j < 4; ++j) acc[i][j] = 0.f;

    for (int k0 = 0; k0 < 1024; k0 += 32) {
        // combine the two partials into the A chunk (registers)
        const short8 q0 = *(const short8*)(p0 + k0);
        const short8 q1 = *(const short8*)(p1 + k0);
        const float2 wv = wrow[(k0 + ka) >> 6];
        union { ushort d[8]; short8 v; } av;
        #pragma unroll
        for (int j = 0; j < 8; ++j)
            av.d[j] = f2bf(bf2f((ushort)q0[j]) * wv.x + bf2f((ushort)q1[j]) * wv.y);
        __syncthreads();
        *(short8*)&As[t * 8] = av.v;
        GL16(b0 + k0, lB0);
        GL16(b1 + k0, lB1);
        __syncthreads();
        short8 af[2], bf[4];
        #pragma unroll
        for (int mi = 0; mi < 2; ++mi)
            af[mi] = *(const short8*)&As[(wr * 32 + mi * 16 + lr) * 32 + lg * 8];
        #pragma unroll
        for (int nj = 0; nj < 4; ++nj)
            bf[nj] = *(const short8*)&Bs[(wc * 64 + nj * 16 + lr) * 32 + lg * 8];
        #pragma unroll
        for (int mi = 0; mi < 2; ++mi)
            #pragma unroll
            for (int nj = 0; nj < 4; ++nj)
                acc[mi][nj] = __builtin_amdgcn_mfma_f32_16x16x32_bf16(
                    af[mi], bf[nj], acc[mi][nj], 0, 0, 0);
    }

    const int row0 = m0 + wr * 32, col0 = n0 + wc * 64;
    #pragma unroll
    for (int mi = 0; mi < 2; ++mi)
        #pragma unroll
        for (int nj = 0; nj < 4; ++nj) {
            const int col = col0 + nj * 16 + lr;
            #pragma unroll
            for (int r = 0; r < 4; ++r) {
                const int row = row0 + mi * 16 + lg * 4 + r;
                Cout[(size_t)row * 1024 + col] = acc[mi][nj][r] + bias[col];
            }
        }
}

// ---------------------------------------------------------------------------
extern "C" void kernel_launch(void* const* d_in, const int* in_sizes, int n_in,
                              void* d_out, int out_size, void* d_ws, size_t ws_size,
                              hipStream_t stream)
{
    const float* primary = (const float*)d_in[0];
    const float* context = (const float*)d_in[1];
    const int*   pmask   = (const int*)d_in[2];
    const int*   amask   = (const int*)d_in[3];
    const float* Wq      = (const float*)d_in[4];
    const float* Wk      = (const float*)d_in[5];
    const float* Wv      = (const float*)d_in[6];
    const float* Wo      = (const float*)d_in[7];
    const float* bo      = (const float*)d_in[8];
    float* out = (float*)d_out;

    char* w8 = (char*)d_ws;
    ushort* Pb  = (ushort*)(w8 + 0);          // dead after gemm_qkv -> Op alias
    ushort* Cb  = (ushort*)(w8 + 8388608);
    ushort* Qb  = (ushort*)(w8 + 16777216);
    ushort* Kb  = (ushort*)(w8 + 25165824);
    ushort* Vb  = (ushort*)(w8 + 33554432);
    ushort* Wqt = (ushort*)(w8 + 50331648);   // dead after gemm_qkv -> ml alias
    ushort* Wkt = (ushort*)(w8 + 52428800);   // dead after gemm_qkv -> wbuf alias
    ushort* Wvt = (ushort*)(w8 + 54525952);
    ushort* Wot = (ushort*)(w8 + 56623104);
    int*    clsp = (int*)(w8 + 58720256);
    ushort* Op   = Pb;                        // 2 x 8.4 MB partials (Pb+Cb)
    float2* mlp  = (float2*)Wqt;              // 1 MB
    float2* wbuf = (float2*)Wkt;              // 512 KB

    cvt_both<<<8192, 256, 0, stream>>>(primary, context, Pb, Cb);
    wtrans4<<<dim3(16, 16, 4), 256, 0, stream>>>(Wq, Wk, Wv, Wo, Wqt, Wkt, Wvt, Wot);
    mask_classify<<<NB * 32 * 32, 256, 0, stream>>>(amask, pmask, clsp);
    gemm_qkv<<<dim3(8, 32, 3), 256, 0, stream>>>(Pb, Cb, Wqt, Wkt, Wvt, Qb, Kb, Vb);
    attn_mfma<<<dim3(16, 16, 4), 256, 0, stream>>>(Qb, Kb, Vb, amask, pmask, clsp, Op, mlp);
    mkw<<<256, 256, 0, stream>>>(mlp, wbuf);
    gemm_out_fused<<<dim3(8, 64), 256, 0, stream>>>(Op, wbuf, Wot, bo, out);
}

// Round 12
// 134.910 us; speedup vs baseline: 1.1129x; 1.1129x over previous
//
#include <hip/hip_runtime.h>

#define NB 2
#define LX 2048
#define LZ 2048
#define HH 16
#define DA 64
#define DM 64
#define HD 1024
#define KVS 2048              // fused K|V buffer row stride
#define MINF  -1000000.0f
#define QSC   0.1803368801f   // 0.125 * log2(e): softmax done in base-2 domain
#define DTHR  8.0f            // defer-max threshold (base-2): P <= 2^8

typedef __attribute__((ext_vector_type(8))) short short8;
typedef __attribute__((ext_vector_type(4))) float f32x4;

static __device__ __forceinline__ ushort f2bf(float f) {
    union { float f; uint32_t u; } c; c.f = f;
    return (ushort)((c.u + 0x7FFFu + ((c.u >> 16) & 1u)) >> 16);
}

static __device__ __forceinline__ float bf2f(ushort u) {
    union { uint32_t u; float f; } c; c.u = (uint32_t)u << 16;
    return c.f;
}

static __device__ __forceinline__ uint32_t cvtpk(float lo, float hi) {
    uint32_t r;
    asm("v_cvt_pk_bf16_f32 %0, %1, %2" : "=v"(r) : "v"(lo), "v"(hi));
    return r;
}

#define GL16(g, l) __builtin_amdgcn_global_load_lds( \
    (const __attribute__((address_space(1))) void*)(g), \
    (__attribute__((address_space(3))) void*)(l), 16, 0, 0)

// ---------------------------------------------------------------------------
// Fused preprocessing, one launch (11264 blocks):
//   [0,8192)      fp32->bf16 of both activations
//   [8192,9216)   4 weight transposes (f32 [K][N] -> bf16 [N][K])
//   [9216,11264)  mask tile classification (0 all-masked / 1 all-pass / 2 mix)
// ---------------------------------------------------------------------------
__global__ __launch_bounds__(256) void prep(
    const float* __restrict__ pA, const float* __restrict__ pB,
    ushort* __restrict__ oA, ushort* __restrict__ oB,
    const float* __restrict__ W0, const float* __restrict__ W1,
    const float* __restrict__ W2, const float* __restrict__ W3,
    ushort* __restrict__ T0, ushort* __restrict__ T1,
    ushort* __restrict__ T2, ushort* __restrict__ T3,
    const int* __restrict__ amask, const int* __restrict__ pmask,
    int* __restrict__ cls)
{
    const int fid = blockIdx.x;
    const int t = threadIdx.x;
    if (fid < 8192) {
        const int i = fid * 256 + t;
        const float* in = (i < 1048576) ? pA : pB;
        ushort* out = (i < 1048576) ? oA : oB;
        const int j = i & 1048575;
        float4 v = ((const float4*)in)[j];
        ushort4 o;
        o.x = f2bf(v.x); o.y = f2bf(v.y); o.z = f2bf(v.z); o.w = f2bf(v.w);
        ((ushort4*)out)[j] = o;
    } else if (fid < 9216) {
        __shared__ ushort Ls[64][72];
        const int id2 = fid - 8192;                 // 0..1023
        const int zz = id2 >> 8, rem = id2 & 255;
        const float* W = (zz == 0) ? W0 : (zz == 1) ? W1 : (zz == 2) ? W2 : W3;
        ushort* Wt = (zz == 0) ? T0 : (zz == 1) ? T1 : (zz == 2) ? T2 : T3;
        const int n0 = (rem & 15) * 64, k0 = (rem >> 4) * 64;
        const int rr = t >> 4, c4 = (t & 15) * 4;
        #pragma unroll
        for (int i = 0; i < 4; ++i) {
            const int r = rr + i * 16;
            float4 v = *(const float4*)&W[(size_t)(k0 + r) * 1024 + n0 + c4];
            Ls[c4 + 0][r] = f2bf(v.x);
            Ls[c4 + 1][r] = f2bf(v.y);
            Ls[c4 + 2][r] = f2bf(v.z);
            Ls[c4 + 3][r] = f2bf(v.w);
        }
        __syncthreads();
        const int n = t >> 2, kc = (t & 3) * 16;
        *(short8*)&Wt[(size_t)(n0 + n) * 1024 + k0 + kc]     = *(const short8*)&Ls[n][kc];
        *(short8*)&Wt[(size_t)(n0 + n) * 1024 + k0 + kc + 8] = *(const short8*)&Ls[n][kc + 8];
    } else {
        const int bid = fid - 9216;                 // 0..2047
        const int b = bid >> 10, xb = (bid >> 5) & 31, zb = bid & 31;
        int andv = 1, orv = 0;
        #pragma unroll
        for (int i = 0; i < 16; ++i) {
            const int e = t + i * 256;
            const int r = e >> 6, z = e & 63;
            const int m = amask[((size_t)b * LX + xb * 64 + r) * LZ + zb * 64 + z];
            const int p = pmask[(size_t)b * LZ + zb * 64 + z];
            const int v = (m != 0) & (p != 0);
            andv &= v; orv |= v;
        }
        __shared__ int sa[256];
        __shared__ int so[256];
        sa[t] = andv; so[t] = orv;
        __syncthreads();
        for (int s = 128; s > 0; s >>= 1) {
            if (t < s) { sa[t] &= sa[t + s]; so[t] |= so[t + s]; }
            __syncthreads();
        }
        if (t == 0) cls[bid] = so[0] ? (sa[0] ? 1 : 2) : 0;
    }
}

// ---------------------------------------------------------------------------
// Fused Q + KV projection GEMM (m97 structure, 128x128 tile, BK=32).
// bx<8: Q = primary @ WqT (pre-scaled by QSC), out stride 1024.
// bx>=8: [K|V] = context @ [WkT;WvT] (2048 rows contiguous), out stride 2048.
// ---------------------------------------------------------------------------
__global__ __launch_bounds__(256) void gemm_qkv(
    const ushort* __restrict__ Pb, const ushort* __restrict__ Cb,
    const ushort* __restrict__ Wqt, const ushort* __restrict__ Wkvt,
    ushort* __restrict__ Qb, ushort* __restrict__ KV)
{
    const int bx = blockIdx.x;
    const bool isQ = bx < 8;
    const ushort* A  = isQ ? Pb : Cb;
    const ushort* Bt = isQ ? Wqt : Wkvt;
    ushort* Cout = isQ ? Qb : KV;
    const int n0 = (isQ ? bx : bx - 8) * 128;
    const int ostr = isQ ? 1024 : KVS;
    const float osc = isQ ? QSC : 1.0f;

    __shared__ ushort As[128 * 32];
    __shared__ ushort Bs[128 * 32];
    const int t = threadIdx.x;
    const int w = t >> 6, l = t & 63, lr = l & 15, lg = l >> 4;
    const int wr = w >> 1, wc = w & 1;
    const int m0 = blockIdx.y * 128;

    const int c0 = t, c1 = t + 256;
    const ushort* a0 = &A[(size_t)(m0 + (c0 >> 2)) * 1024 + (c0 & 3) * 8];
    const ushort* a1 = &A[(size_t)(m0 + (c1 >> 2)) * 1024 + (c1 & 3) * 8];
    const ushort* b0 = &Bt[(size_t)(n0 + (c0 >> 2)) * 1024 + (c0 & 3) * 8];
    const ushort* b1 = &Bt[(size_t)(n0 + (c1 >> 2)) * 1024 + (c1 & 3) * 8];
    ushort* lA0 = &As[w * 512];
    ushort* lA1 = &As[(4 + w) * 512];
    ushort* lB0 = &Bs[w * 512];
    ushort* lB1 = &Bs[(4 + w) * 512];

    f32x4 acc[4][4];
    #pragma unroll
    for (int i = 0; i < 4; ++i)
        #pragma unroll
        for (int j = 0; j < 4; ++j) acc[i][j] = 0.f;

    for (int k0 = 0; k0 < 1024; k0 += 32) {
        __syncthreads();
        GL16(a0 + k0, lA0);
        GL16(a1 + k0, lA1);
        GL16(b0 + k0, lB0);
        GL16(b1 + k0, lB1);
        __syncthreads();
        short8 af[4], bf[4];
        #pragma unroll
        for (int mi = 0; mi < 4; ++mi)
            af[mi] = *(const short8*)&As[(wr * 64 + mi * 16 + lr) * 32 + lg * 8];
        #pragma unroll
        for (int nj = 0; nj < 4; ++nj)
            bf[nj] = *(const short8*)&Bs[(wc * 64 + nj * 16 + lr) * 32 + lg * 8];
        #pragma unroll
        for (int mi = 0; mi < 4; ++mi)
            #pragma unroll
            for (int nj = 0; nj < 4; ++nj)
                acc[mi][nj] = __builtin_amdgcn_mfma_f32_16x16x32_bf16(
                    af[mi], bf[nj], acc[mi][nj], 0, 0, 0);
    }

    const int row0 = m0 + wr * 64, col0 = n0 + wc * 64;
    #pragma unroll
    for (int mi = 0; mi < 4; ++mi)
        #pragma unroll
        for (int nj = 0; nj < 4; ++nj) {
            const int col = col0 + nj * 16 + lr;
            #pragma unroll
            for (int r = 0; r < 4; ++r) {
                const int row = row0 + mi * 16 + lg * 4 + r;
                Cout[(size_t)row * ostr + col] = f2bf(acc[mi][nj][r] * osc);
            }
        }
}

// ---------------------------------------------------------------------------
// MFMA flash attention (round-8 structure: best measured) + balanced XCD
// clustering. Split-KV x2, 64 q-rows/block, single K/V LDS buffer, 2 barriers
// per tile, 2048 blocks. K/V read from fused KV buffer (stride 2048) -> each
// (h,b,sKV) group's 512 KB K/V is L2-resident on its XCD. Swapped QK^T;
// zero-shuffle PV (sigma z-order); defer-max; deferred l-reduction;
// setprio(1) on MFMA. Writes PARTIAL O (bf16) + (m,l) f32.
// ---------------------------------------------------------------------------
__global__ __launch_bounds__(256, 4) void attn_mfma(
    const ushort* __restrict__ Qg, const ushort* __restrict__ KVg,
    const int* __restrict__ amask, const int* __restrict__ pmask,
    const int* __restrict__ cls, ushort* __restrict__ Op,
    float2* __restrict__ ml)
{
    __shared__ ushort Ks[64 * 72];   // [z][d], pad 72
    __shared__ ushort Vt[64 * 64];   // [m][z], chunk-XOR swizzled

    const int t = threadIdx.x, w = t >> 6, l = t & 63, lr = l & 15, lg = l >> 4;
    // balanced XCD clustering: XCD x gets (h,bs) groups {x, x+8, ..., x+56}
    const int flat = blockIdx.x + 32 * (blockIdx.y + 16 * blockIdx.z); // 0..2047
    const int xcd = flat & 7, ii = flat >> 3;       // ii 0..255
    const int g = xcd + 8 * (ii >> 5);              // 0..63
    const int xr_ = ii & 31;
    const int h = g & 15, bs = g >> 4;              // bs 0..3
    const int b = bs & 1, sKV = bs >> 1;
    const int fx = (xr_ & 1) ? 31 - (xr_ >> 1) : (xr_ >> 1);
    const int qb = b ? 31 - fx : fx;
    const int qw = qb * 64 + w * 16;

    // Q B-frags: lane holds Q[q = lr][d = ks*32 + lg*8 .. +8]
    short8 qf[2];
    #pragma unroll
    for (int ks = 0; ks < 2; ++ks)
        qf[ks] = *(const short8*)&Qg[(size_t)(b * LX + qw + lr) * HD
                                     + h * DA + ks * 32 + lg * 8];

    float mrun = -1e30f, lrun = 0.f;   // lrun = per-lane partial (16 slots)
    f32x4 o[4];
    #pragma unroll
    for (int mj = 0; mj < 4; ++mj) o[mj] = 0.f;

    const int kz = t >> 2, kc = (t & 3) * 16;      // K staging
    const int vz = (t >> 3) * 2, vc = (t & 7) * 8; // V staging (2 rows x 8 cols)

    for (int zb = sKV; zb < LZ / 64; zb += 2) {
        const int cl = cls[b * 1024 + qb * 32 + zb];   // uniform across block
        if (cl == 0) continue;
        const int z0 = zb * 64;

        __syncthreads();                // prior tile's LDS reads done
        {
            const ushort* kp = &KVg[(size_t)(b * LZ + z0 + kz) * KVS + h * DA + kc];
            *(short8*)&Ks[kz * 72 + kc]     = *(const short8*)kp;
            *(short8*)&Ks[kz * 72 + kc + 8] = *(const short8*)(kp + 8);
            const ushort* vp = &KVg[(size_t)(b * LZ + z0 + vz) * KVS + 1024 + h * DM + vc];
            short8 v0 = *(const short8*)vp;
            short8 v1 = *(const short8*)(vp + KVS);
            const int zc = vz >> 3, zo = vz & 7;
            #pragma unroll
            for (int j = 0; j < 8; ++j) {
                const int m = vc + j;
                const int idx = m * 64 + (((zc ^ m ^ (m >> 3)) & 7) << 3) + zo;
                *(uint32_t*)&Vt[idx] =
                    (uint32_t)(ushort)v0[j] | ((uint32_t)(ushort)v1[j] << 16);
            }
        }
        __syncthreads();

        // ---- S^T = K @ Q : lane holds S[q=lr][z = nj*16 + lg*4 + r] ----
        f32x4 s[4];
        __builtin_amdgcn_s_setprio(1);
        #pragma unroll
        for (int nj = 0; nj < 4; ++nj) {
            const short8 kf0 = *(const short8*)&Ks[(nj * 16 + lr) * 72 + lg * 8];
            const short8 kf1 = *(const short8*)&Ks[(nj * 16 + lr) * 72 + 32 + lg * 8];
            f32x4 z4 = 0.f;
            z4 = __builtin_amdgcn_mfma_f32_16x16x32_bf16(kf0, qf[0], z4, 0, 0, 0);
            z4 = __builtin_amdgcn_mfma_f32_16x16x32_bf16(kf1, qf[1], z4, 0, 0, 0);
            s[nj] = z4;
        }
        __builtin_amdgcn_s_setprio(0);
        // ---- mask (mixed tiles only) ----
        if (cl == 2) {
            const size_t arow = (size_t)(b * LX + qw + lr) * LZ + z0;
            #pragma unroll
            for (int nj = 0; nj < 4; ++nj)
                #pragma unroll
                for (int r = 0; r < 4; ++r) {
                    const int z = nj * 16 + lg * 4 + r;
                    const int ok = (amask[arow + z] != 0) & (pmask[b * LZ + z0 + z] != 0);
                    if (!ok) s[nj][r] = MINF;
                }
        }
        // ---- online softmax, base-2, defer-max (row stats live at q=lr) ----
        {
            float pm = s[0][0];
            #pragma unroll
            for (int nj = 0; nj < 4; ++nj)
                #pragma unroll
                for (int r = 0; r < 4; ++r) pm = fmaxf(pm, s[nj][r]);
            pm = fmaxf(pm, __shfl_xor(pm, 16));
            pm = fmaxf(pm, __shfl_xor(pm, 32));
            if (__any(pm > mrun + DTHR)) {
                const float mn = fmaxf(mrun, pm);
                const float al = exp2f(mrun - mn);
                mrun = mn;
                lrun *= al;
                #pragma unroll
                for (int r = 0; r < 4; ++r) {
                    const float alq = __shfl(al, (lg << 2) + r);
                    #pragma unroll
                    for (int mj = 0; mj < 4; ++mj) o[mj][r] *= alq;
                }
            }
            #pragma unroll
            for (int nj = 0; nj < 4; ++nj)
                #pragma unroll
                for (int r = 0; r < 4; ++r) {
                    const float p = exp2f(s[nj][r] - mrun);
                    s[nj][r] = p;
                    lrun += p;     // per-lane partial; cross-lane reduce at end
                }
        }
        // ---- P -> PV A-frags: pack own registers (sigma z-order) ----
        short8 pa[2];
        {
            uint32_t pk01[4], pk23[4];
            #pragma unroll
            for (int nj = 0; nj < 4; ++nj) {
                pk01[nj] = cvtpk(s[nj][0], s[nj][1]);
                pk23[nj] = cvtpk(s[nj][2], s[nj][3]);
            }
            #pragma unroll
            for (int ks = 0; ks < 2; ++ks) {
                union { uint32_t d[4]; short8 v; } u;
                u.d[0] = pk01[2 * ks];
                u.d[1] = pk23[2 * ks];
                u.d[2] = pk01[2 * ks + 1];
                u.d[3] = pk23[2 * ks + 1];
                pa[ks] = u.v;
            }
        }
        // ---- O += P @ V (V-frags in matching sigma z-order, 4x b64 each) ----
        __builtin_amdgcn_s_setprio(1);
        #pragma unroll
        for (int mj = 0; mj < 4; ++mj) {
            const int m_ = mj * 16 + lr;
            const int xr = (m_ ^ (m_ >> 3)) & 7;
            const int czb = lg >> 1;
            const int zo = (lg & 1) * 4;
            #pragma unroll
            for (int ks = 0; ks < 2; ++ks) {
                const int clo = (ks * 4 + czb) ^ xr;
                const int chi = (ks * 4 + 2 + czb) ^ xr;
                const uint2 lo = *(const uint2*)&Vt[m_ * 64 + ((clo & 7) << 3) + zo];
                const uint2 hi = *(const uint2*)&Vt[m_ * 64 + ((chi & 7) << 3) + zo];
                union { uint32_t d[4]; short8 v; } u;
                u.d[0] = lo.x; u.d[1] = lo.y; u.d[2] = hi.x; u.d[3] = hi.y;
                o[mj] = __builtin_amdgcn_mfma_f32_16x16x32_bf16(pa[ks], u.v, o[mj], 0, 0, 0);
            }
        }
        __builtin_amdgcn_s_setprio(0);
    }

    // ---- epilogue: finish l reduction, store partials (no normalize) ----
    lrun += __shfl_xor(lrun, 16);
    lrun += __shfl_xor(lrun, 32);
    if (l < 16)
        ml[(size_t)((sKV * NB + b) * HH + h) * LX + qw + l] = make_float2(mrun, lrun);
    const size_t ob = (size_t)((sKV * NB + b) * LX + qw) * HD + h * DM;
    #pragma unroll
    for (int r = 0; r < 4; ++r)
        #pragma unroll
        for (int mj = 0; mj < 4; ++mj)
            Op[ob + (size_t)((lg << 2) + r) * HD + mj * 16 + lr] = f2bf(o[mj][r]);
}

// ---------------------------------------------------------------------------
// Output GEMM with fused split-KV combine AND in-kernel combine weights.
// Per block: compute w = (exp2(m_i - M)/L) for its 64 rows x 16 heads into
// padded LDS, then build A on the fly from the two partials during staging.
// Tile 64x128, BK=32, 4 waves; fp32 out + bias.
// ---------------------------------------------------------------------------
__global__ __launch_bounds__(256) void gemm_out_fused(
    const ushort* __restrict__ Op, const float2* __restrict__ ml,
    const ushort* __restrict__ Bt, const float* __restrict__ bias,
    float* __restrict__ Cout)
{
    __shared__ ushort As[64 * 32];
    __shared__ ushort Bs[128 * 32];
    __shared__ float2 Wl[64][17];
    const int t = threadIdx.x;
    const int w = t >> 6, l = t & 63, lr = l & 15, lg = l >> 4;
    const int wr = w >> 1, wc = w & 1;
    const int n0 = blockIdx.x * 128, m0 = blockIdx.y * 64;

    // combine weights for this block's 64 rows x 16 heads
    {
        const int e = t * 4;
        #pragma unroll
        for (int j = 0; j < 4; ++j) {
            const int rl = (e + j) >> 4, hh = (e + j) & 15;
            const int ra = m0 + rl;
            const int bb = ra >> 11, xx = ra & 2047;
            const float2 a0 = ml[(size_t)(bb * HH + hh) * LX + xx];
            const float2 a1 = ml[(size_t)((NB + bb) * HH + hh) * LX + xx];
            const float M = fmaxf(a0.x, a1.x);
            const float w0 = exp2f(a0.x - M), w1 = exp2f(a1.x - M);
            const float inv = 1.f / fmaxf(a0.y * w0 + a1.y * w1, 1e-37f);
            Wl[rl][hh] = make_float2(w0 * inv, w1 * inv);
        }
    }
    __syncthreads();

    const int ra = m0 + (t >> 2), ka = (t & 3) * 8;
    const ushort* p0 = &Op[(size_t)ra * HD + ka];
    const ushort* p1 = p0 + (size_t)NB * LX * HD;
    const ushort* b0 = &Bt[(size_t)(n0 + (t >> 2)) * 1024 + ka];
    const ushort* b1 = &Bt[(size_t)(n0 + 64 + (t >> 2)) * 1024 + ka];
    ushort* lB0 = &Bs[w * 512];
    ushort* lB1 = &Bs[(4 + w) * 512];

    f32x4 acc[2][4];
    #pragma unroll
    for (int i = 0; i < 2; ++i)
        #pragma unroll
        for (int j = 0; j < 4; ++j) acc[i][j] = 0.f;

    for (int k0 = 0; k0 < 1024; k0 += 32) {
        const short8 q0 = *(const short8*)(p0 + k0);
        const short8 q1 = *(const short8*)(p1 + k0);
        const float2 wv = Wl[t >> 2][(k0 + ka) >> 6];
        union { ushort d[8]; short8 v; } av;
        #pragma unroll
        for (int j = 0; j < 8; ++j)
            av.d[j] = f2bf(bf2f((ushort)q0[j]) * wv.x + bf2f((ushort)q1[j]) * wv.y);
        __syncthreads();
        *(short8*)&As[t * 8] = av.v;
        GL16(b0 + k0, lB0);
        GL16(b1 + k0, lB1);
        __syncthreads();
        short8 af[2], bf[4];
        #pragma unroll
        for (int mi = 0; mi < 2; ++mi)
            af[mi] = *(const short8*)&As[(wr * 32 + mi * 16 + lr) * 32 + lg * 8];
        #pragma unroll
        for (int nj = 0; nj < 4; ++nj)
            bf[nj] = *(const short8*)&Bs[(wc * 64 + nj * 16 + lr) * 32 + lg * 8];
        #pragma unroll
        for (int mi = 0; mi < 2; ++mi)
            #pragma unroll
            for (int nj = 0; nj < 4; ++nj)
                acc[mi][nj] = __builtin_amdgcn_mfma_f32_16x16x32_bf16(
                    af[mi], bf[nj], acc[mi][nj], 0, 0, 0);
    }

    const int row0 = m0 + wr * 32, col0 = n0 + wc * 64;
    #pragma unroll
    for (int mi = 0; mi < 2; ++mi)
        #pragma unroll
        for (int nj = 0; nj < 4; ++nj) {
            const int col = col0 + nj * 16 + lr;
            #pragma unroll
            for (int r = 0; r < 4; ++r) {
                const int row = row0 + mi * 16 + lg * 4 + r;
                Cout[(size_t)row * 1024 + col] = acc[mi][nj][r] + bias[col];
            }
        }
}

// ---------------------------------------------------------------------------
extern "C" void kernel_launch(void* const* d_in, const int* in_sizes, int n_in,
                              void* d_out, int out_size, void* d_ws, size_t ws_size,
                              hipStream_t stream)
{
    const float* primary = (const float*)d_in[0];
    const float* context = (const float*)d_in[1];
    const int*   pmask   = (const int*)d_in[2];
    const int*   amask   = (const int*)d_in[3];
    const float* Wq      = (const float*)d_in[4];
    const float* Wk      = (const float*)d_in[5];
    const float* Wv      = (const float*)d_in[6];
    const float* Wo      = (const float*)d_in[7];
    const float* bo      = (const float*)d_in[8];
    float* out = (float*)d_out;

    char* w8 = (char*)d_ws;
    ushort* Pb  = (ushort*)(w8 + 0);          // dead after gemm_qkv -> Op alias
    ushort* Cb  = (ushort*)(w8 + 8388608);
    ushort* Qb  = (ushort*)(w8 + 16777216);
    ushort* KV  = (ushort*)(w8 + 25165824);   // [4096][2048] bf16 = 16 MB
    ushort* Wqt = (ushort*)(w8 + 50331648);   // dead after gemm_qkv -> ml alias
    ushort* Wkt = (ushort*)(w8 + 52428800);   // [WkT;WvT] fused 2048x1024
    ushort* Wvt = (ushort*)(w8 + 54525952);
    ushort* Wot = (ushort*)(w8 + 56623104);
    int*    clsp = (int*)(w8 + 58720256);
    ushort* Op   = Pb;                        // 2 x 8.4 MB partials (Pb+Cb)
    float2* mlp  = (float2*)Wqt;              // 1 MB

    prep<<<11264, 256, 0, stream>>>(primary, context, Pb, Cb,
                                    Wq, Wk, Wv, Wo, Wqt, Wkt, Wvt, Wot,
                                    amask, pmask, clsp);
    gemm_qkv<<<dim3(24, 32), 256, 0, stream>>>(Pb, Cb, Wqt, Wkt, Qb, KV);
    attn_mfma<<<dim3(32, 16, 4), 256, 0, stream>>>(Qb, KV, amask, pmask, clsp, Op, mlp);
    gemm_out_fused<<<dim3(8, 64), 256, 0, stream>>>(Op, mlp, Wot, bo, out);
}